// Round 14
// baseline (116.333 us; speedup 1.0000x reference)
//
#include <hip/hip_runtime.h>
#include <hip/hip_fp16.h>
#include <math.h>

#define N_NODES 50000
#define N_EDGES 1000000
#define N_HID 64
#define N_GRAPHS 500
#define IN_DIM 4
#define NPAD 50048

#define BK_SHIFT 7
#define BK_NODES 128                      // nodes per bucket
#define NBUCK 391                         // ceil(50000/128)
#define BCAP 3072                         // mean 2560 + 10 sigma
#define EPT 16                            // edges per thread in k_bin
#define EPW (EPT * 256)                   // 4096 edges per WG
#define NWG_BIN ((N_EDGES + EPW - 1) / EPW)

// ---------- init: bcur, gstart/gend, pooled sums ----------
__global__ void k_init(int* bcur, int* gstart, int* gend, float* sums) {
    int i = blockIdx.x * blockDim.x + threadIdx.x;
    if (i < 512) { bcur[i] = 0; gstart[i] = 0; gend[i] = 0; }
    if (i < N_GRAPHS * N_HID) sums[i] = 0.f;
}

// ---------- pass A: bin packed (src<<7|dstlocal) by dst bucket ----------
// single-histogram: pass-1 atomic return value IS the local offset.
__global__ void k_bin(const int* __restrict__ ei, int* bcur, int* __restrict__ P) {
    __shared__ int hist[NBUCK];
    __shared__ int base[NBUCK];
    int t = threadIdx.x;
    int wg0 = blockIdx.x * EPW;
    for (int b = t; b < NBUCK; b += 256) hist[b] = 0;
    __syncthreads();

    const int4* s4 = (const int4*)ei;
    const int4* d4 = (const int4*)(ei + N_EDGES);
    int rs[EPT], rd[EPT], rl[EPT];
#pragma unroll
    for (int i = 0; i < 4; ++i) {
        int e = wg0 + (i * 256 + t) * 4;
        if (e < N_EDGES) {
            int4 vs = s4[e >> 2];
            int4 vd = d4[e >> 2];
            rs[i * 4 + 0] = vs.x; rd[i * 4 + 0] = vd.x;
            rs[i * 4 + 1] = vs.y; rd[i * 4 + 1] = vd.y;
            rs[i * 4 + 2] = vs.z; rd[i * 4 + 2] = vd.z;
            rs[i * 4 + 3] = vs.w; rd[i * 4 + 3] = vd.w;
            rl[i * 4 + 0] = atomicAdd(&hist[vd.x >> BK_SHIFT], 1);
            rl[i * 4 + 1] = atomicAdd(&hist[vd.y >> BK_SHIFT], 1);
            rl[i * 4 + 2] = atomicAdd(&hist[vd.z >> BK_SHIFT], 1);
            rl[i * 4 + 3] = atomicAdd(&hist[vd.w >> BK_SHIFT], 1);
        } else {
            rd[i * 4 + 0] = rd[i * 4 + 1] = rd[i * 4 + 2] = rd[i * 4 + 3] = -1;
        }
    }
    __syncthreads();
    for (int b = t; b < NBUCK; b += 256) {
        int h = hist[b];
        base[b] = h ? atomicAdd(&bcur[b], h) : 0;
    }
    __syncthreads();
#pragma unroll
    for (int i = 0; i < EPT; ++i) {
        if (rd[i] >= 0) {
            int bk = rd[i] >> BK_SHIFT;
            int loc = base[bk] + rl[i];
            if (loc > BCAP - 1) loc = BCAP - 1;   // overflow guard (never expected)
            P[(size_t)bk * BCAP + loc] = (rs[i] << BK_SHIFT) | (rd[i] & (BK_NODES - 1));
        }
    }
}

// ---------- pass B: per-bucket counting sort -> CSR rows + dis + xs=x*dis ----------
__global__ void k_build(const int* __restrict__ bcur, const int* __restrict__ P,
                        const float* __restrict__ x,
                        int* __restrict__ srcidx, int* __restrict__ offs,
                        int* __restrict__ endp, float* __restrict__ dis,
                        float* __restrict__ xs) {
    __shared__ int sp[BCAP];
    __shared__ int scnt[BK_NODES];
    __shared__ int sscan[BK_NODES];
    __shared__ int scur[BK_NODES];
    int b = blockIdx.x;
    int t = threadIdx.x;
    int n = bcur[b];
    if (n > BCAP) n = BCAP;
    if (t < BK_NODES) scnt[t] = 0;
    __syncthreads();
    for (int i = t; i < n; i += 256) {
        int v = P[(size_t)b * BCAP + i];
        sp[i] = v;
        atomicAdd(&scnt[v & (BK_NODES - 1)], 1);
    }
    __syncthreads();
    if (t < BK_NODES) sscan[t] = scnt[t];
    __syncthreads();
    for (int d = 1; d < BK_NODES; d <<= 1) {
        int v = 0;
        if (t < BK_NODES && t >= d) v = sscan[t - d];
        __syncthreads();
        if (t < BK_NODES) sscan[t] += v;
        __syncthreads();
    }
    if (t < BK_NODES) {
        int excl = sscan[t] - scnt[t];
        scur[t] = excl;
        int node = b * BK_NODES + t;
        if (node < N_NODES) {
            int o = b * BCAP + excl;
            offs[node] = o;
            endp[node] = o + scnt[t];
            float dd = 1.0f / sqrtf((float)(scnt[t] + 1));
            dis[node] = dd;
            float4 xv = ((const float4*)x)[node];
            xv.x *= dd; xv.y *= dd; xv.z *= dd; xv.w *= dd;
            ((float4*)xs)[node] = xv;
        }
    }
    __syncthreads();
    for (int i = t; i < n; i += 256) {
        int v = sp[i];
        int ln = v & (BK_NODES - 1);
        int pos = b * BCAP + atomicAdd(&scur[ln], 1);
        srcidx[pos] = v >> BK_SHIFT;
    }
}

// ---------- fused layer 1: gbounds + (Ahat*X) + split fp16 h1 tables ----------
// h1a = feats 0..31, h1b = feats 32..63 ; each row 64 B (one cache line) so each
// gather sub-pass in k_layer2 works a 3.2 MB table that fits an XCD's 4 MB L2.
__global__ void k_layer1(const float* __restrict__ xs, const int* __restrict__ offs,
                         const int* __restrict__ endp, const int* __restrict__ srcidx,
                         const float* __restrict__ dis, const int* __restrict__ batch,
                         const float* __restrict__ W1, const float* __restrict__ b1,
                         int* __restrict__ gstart, int* __restrict__ gend,
                         __half* __restrict__ h1a, __half* __restrict__ h1b) {
    __shared__ float4 sagg[256];
    __shared__ float sdis[256];
    __shared__ float sW1[IN_DIM * N_HID];
    __shared__ float sb1[N_HID];
    int t = threadIdx.x;
    int nb = blockIdx.x * 256;
    int i = nb + t;
    sW1[t] = W1[t];                        // 256 = IN_DIM*N_HID
    if (t < N_HID) sb1[t] = b1[t];
    if (i < N_NODES) {
        int g = batch[i];
        if (i == 0 || batch[i - 1] != g) gstart[g] = i;          // no atomics:
        if (i == N_NODES - 1 || batch[i + 1] != g) gend[g] = i + 1;  // batch sorted
        const float4* xs4 = (const float4*)xs;
        float4 a0 = xs4[i];                // self-loop (xs = x*dis)
        float4 a1 = make_float4(0.f, 0.f, 0.f, 0.f);
        float4 a2 = a1, a3 = a1;
        int q = offs[i], e = endp[i];
        for (; q + 4 <= e; q += 4) {       // 4 independent gathers in flight
            int i0 = srcidx[q], i1 = srcidx[q + 1], i2 = srcidx[q + 2], i3 = srcidx[q + 3];
            float4 v0 = xs4[i0], v1 = xs4[i1], v2 = xs4[i2], v3 = xs4[i3];
            a0.x += v0.x; a0.y += v0.y; a0.z += v0.z; a0.w += v0.w;
            a1.x += v1.x; a1.y += v1.y; a1.z += v1.z; a1.w += v1.w;
            a2.x += v2.x; a2.y += v2.y; a2.z += v2.z; a2.w += v2.w;
            a3.x += v3.x; a3.y += v3.y; a3.z += v3.z; a3.w += v3.w;
        }
        for (; q < e; ++q) {
            float4 v = xs4[srcidx[q]];
            a0.x += v.x; a0.y += v.y; a0.z += v.z; a0.w += v.w;
        }
        float dd = dis[i];
        float4 r;
        r.x = (a0.x + a1.x + a2.x + a3.x) * dd;
        r.y = (a0.y + a1.y + a2.y + a3.y) * dd;
        r.z = (a0.z + a1.z + a2.z + a3.z) * dd;
        r.w = (a0.w + a1.w + a2.w + a3.w) * dd;
        sagg[t] = r;
        sdis[t] = dd;
    } else {
        sagg[t] = make_float4(0.f, 0.f, 0.f, 0.f);
        sdis[t] = 0.f;
    }
    __syncthreads();
    int w = t >> 6, j = t & 63;
    float w0 = sW1[0 * N_HID + j], w1 = sW1[1 * N_HID + j];
    float w2 = sW1[2 * N_HID + j], w3 = sW1[3 * N_HID + j];
    float bj = sb1[j];
    for (int n = 0; n < 64; ++n) {
        int local = w * 64 + n;
        int node = nb + local;
        if (node >= N_NODES) break;        // wave-uniform (j not involved)
        float4 a = sagg[local];            // LDS broadcast
        float acc = a.x * w0 + a.y * w1 + a.z * w2 + a.w * w3 + bj;
        acc = acc > 0.f ? acc : expm1f(acc);
        __half hv = __float2half_rn(acc * sdis[local]);
        if (j < 32) h1a[(size_t)node * 32 + j] = hv;
        else        h1b[(size_t)node * 32 + (j - 32)] = hv;
    }
}

// ---------- fp16 chunk accumulate: float2 = 4 halves -> 4 fp32 accs ----------
__device__ inline void acc_half4(float* acc, float2 raw) {
    const __half2* hp = (const __half2*)&raw;
    float2 f0 = __half22float2(hp[0]);
    float2 f1 = __half22float2(hp[1]);
    acc[0] += f0.x; acc[1] += f0.y; acc[2] += f1.x; acc[3] += f1.y;
}

// ---------- fused layer 2: 2-sub-pass L2-resident gather -> GEMM+ELU -> pool ----
// Sub-pass p gathers 64 B rows from a 3.2 MB half-table (fits XCD L2 -> hit
// latency L2-class, not L3-class; round-13 showed the gather is bound by
// outstanding-miss capacity x latency, so halving latency is the lever).
// NOTE: every __shfl must be executed by ALL 64 lanes — ds_bpermute reads 0
// from EXEC-masked source lanes. Only the dependent load/add is predicated.
#define L2_NODES 16
__global__ void k_layer2(const __half* __restrict__ h1a, const __half* __restrict__ h1b,
                         const int* __restrict__ offs, const int* __restrict__ endp,
                         const int* __restrict__ srcidx, const float* __restrict__ dis,
                         const int* __restrict__ batch, const float* __restrict__ W2,
                         const float* __restrict__ b2, float* __restrict__ sums) {
    __shared__ float sAT[N_HID][L2_NODES + 1];   // [k][n] tmp2, then [feat][n] h2
    __shared__ int sbat[L2_NODES];
    int t = threadIdx.x;  // 256
    int nb = blockIdx.x * L2_NODES;              // 50000/16 = 3125 exact, no tail
    if (t < L2_NODES) sbat[t] = batch[nb + t];

    int wv = t >> 6, lane = t & 63;
    int g = lane >> 3, l = lane & 7;             // 8 groups x 8 lanes, float2/lane
#pragma unroll
    for (int p = 0; p < 2; ++p) {
        const float2* hv = (const float2*)(p == 0 ? h1a : h1b);  // 8 float2/row
        // prefetch first node's indices
        int node = nb + wv * 4;
        int start = offs[node], end = endp[node];
        int myidx = (start + lane < end) ? srcidx[start + lane] : 0;
        for (int nn = 0; nn < 4; ++nn) {
            float accA[4] = {0.f, 0.f, 0.f, 0.f};
            float accB[4] = {0.f, 0.f, 0.f, 0.f};
            if (g == 0) acc_half4(accA, hv[(size_t)node * 8 + l]);   // self-loop
            int base = start;
            for (;;) {
                int nc = end - base; if (nc > 64) nc = 64;
                int q = 0;
                for (; q + 16 <= nc; q += 16) {  // 2 loads (16 edges) in flight
                    int s0 = __shfl(myidx, q + g);
                    int s1 = __shfl(myidx, q + 8 + g);
                    float2 r0 = hv[(size_t)s0 * 8 + l];
                    float2 r1 = hv[(size_t)s1 * 8 + l];
                    acc_half4(accA, r0);
                    acc_half4(accB, r1);
                }
                if (q + 8 <= nc) {
                    int s = __shfl(myidx, q + g);
                    acc_half4(accA, hv[(size_t)s * 8 + l]);
                    q += 8;
                }
                if (q < nc) {                    // ragged tail (wave-uniform entry)
                    int s = __shfl(myidx, q + g);    // q<=56 -> q+g<=63, legal
                    if (q + g < nc) acc_half4(accB, hv[(size_t)s * 8 + l]);
                }
                base += 64;
                if (base >= end) break;
                myidx = (base + lane < end) ? srcidx[base + lane] : 0;
            }
            // prefetch NEXT node's indices before the fold (hide srcidx latency)
            int node_n = 0, start_n = 0, end_n = 0, myidx_n = 0;
            if (nn < 3) {
                node_n = nb + wv * 4 + nn + 1;
                start_n = offs[node_n]; end_n = endp[node_n];
                myidx_n = (start_n + lane < end_n) ? srcidx[start_n + lane] : 0;
            }
#pragma unroll
            for (int c = 0; c < 4; ++c) accA[c] += accB[c];
#pragma unroll
            for (int c = 0; c < 4; ++c) {        // fold 8 group-partials
                accA[c] += __shfl_xor(accA[c], 8);
                accA[c] += __shfl_xor(accA[c], 16);
                accA[c] += __shfl_xor(accA[c], 32);
            }
            if (g == 0) {
                int local = wv * 4 + nn;
                float dw = dis[node];
#pragma unroll
                for (int c = 0; c < 4; ++c)
                    sAT[p * 32 + 4 * l + c][local] = accA[c] * dw;
            }
            node = node_n; start = start_n; end = end_n; myidx = myidx_n;
        }
    }
    __syncthreads();

    // ---- phase 2: 16x64 GEMM + bias + ELU (thread = 1 node x 4 feats; W2 via L1) ----
    int tj = t & 15, tn = t >> 4;
    const float4* W2v = (const float4*)W2;   // 16 float4 per k-row
    float4 acc = make_float4(0.f, 0.f, 0.f, 0.f);
#pragma unroll 8
    for (int k = 0; k < N_HID; ++k) {
        float a = sAT[k][tn];                // 16-lane broadcast, conflict-free
        float4 w = W2v[k * 16 + tj];
        acc.x += a * w.x; acc.y += a * w.y; acc.z += a * w.z; acc.w += a * w.w;
    }
    float4 bb = ((const float4*)b2)[tj];
    __syncthreads();   // everyone done reading sAT before overwrite
    {
        float4 r;
        r.x = acc.x + bb.x; r.y = acc.y + bb.y;
        r.z = acc.z + bb.z; r.w = acc.w + bb.w;
        r.x = r.x > 0.f ? r.x : expm1f(r.x);
        r.y = r.y > 0.f ? r.y : expm1f(r.y);
        r.z = r.z > 0.f ? r.z : expm1f(r.z);
        r.w = r.w > 0.f ? r.w : expm1f(r.w);
        sAT[4 * tj + 0][tn] = r.x;           // h2 back into sAT as [feat][node]
        sAT[4 * tj + 1][tn] = r.y;
        sAT[4 * tj + 2][tn] = r.z;
        sAT[4 * tj + 3][tn] = r.w;
    }
    __syncthreads();

    // ---- phase 3: per-graph segment pooling (batch sorted; one wave, lane=feat) ----
    if (t < 64) {
        int s = 0;
        while (s < L2_NODES) {
            int gg = sbat[s];
            int e = s + 1;
            while (e < L2_NODES && sbat[e] == gg) ++e;
            float p = 0.f;
            for (int n = s; n < e; ++n) p += sAT[t][n];
            atomicAdd(&sums[gg * N_HID + t], p);
            s = e;
        }
    }
}

// ---------- final: out[g] = dot(sums[g]/cnt, W3) + b3 ; one wave per graph ----------
__global__ void k_final(const float* __restrict__ sums, const int* __restrict__ gstart,
                        const int* __restrict__ gend, const float* __restrict__ W3,
                        const float* __restrict__ b3, float* __restrict__ out) {
    int gid = blockIdx.x * 4 + (threadIdx.x >> 6);
    int j = threadIdx.x & 63;
    if (gid >= N_GRAPHS) return;
    int cnt = gend[gid] - gstart[gid];
    float v = sums[gid * N_HID + j] / (float)(cnt > 0 ? cnt : 1);
    float p = v * W3[j];
#pragma unroll
    for (int off = 32; off; off >>= 1) p += __shfl_down(p, off);
    if (j == 0) out[gid] = p + b3[0];
}

extern "C" void kernel_launch(void* const* d_in, const int* in_sizes, int n_in,
                              void* d_out, int out_size, void* d_ws, size_t ws_size,
                              hipStream_t stream) {
    const float* x   = (const float*)d_in[0];
    const int*   ei  = (const int*)d_in[1];
    const int*   bat = (const int*)d_in[2];
    const float* W1  = (const float*)d_in[3];
    const float* b1  = (const float*)d_in[4];
    const float* W2  = (const float*)d_in[5];
    const float* b2  = (const float*)d_in[6];
    const float* W3  = (const float*)d_in[7];
    const float* b3  = (const float*)d_in[8];
    float* out = (float*)d_out;

    // ---- workspace ----
    char* w = (char*)d_ws;
    int*   bcur   = (int*)w;   w += 512 * 4;
    int*   offs   = (int*)w;   w += NPAD * 4;
    int*   endp   = (int*)w;   w += NPAD * 4;
    float* dis    = (float*)w; w += NPAD * 4;
    int*   gstart = (int*)w;   w += 512 * 4;
    int*   gend   = (int*)w;   w += 512 * 4;
    float* sums   = (float*)w; w += (size_t)N_GRAPHS * N_HID * 4;  // 128 KB
    float* xs     = (float*)w; w += (size_t)NPAD * IN_DIM * 4;     // 800 KB
    int*   srcidx = (int*)w;   w += (size_t)NBUCK * BCAP * 4;      // 4.8 MB
    int*   P      = (int*)w;   w += (size_t)NBUCK * BCAP * 4;      // 4.8 MB
    __half* h1a   = (__half*)w; w += (size_t)NPAD * 32 * 2;        // 3.2 MB
    __half* h1b   = (__half*)w; w += (size_t)NPAD * 32 * 2;        // 3.2 MB

    const int B = 256;
    const int gN = (N_NODES + B - 1) / B;

    k_init<<<(N_GRAPHS * N_HID + B - 1) / B, B, 0, stream>>>(bcur, gstart, gend, sums);
    k_bin<<<NWG_BIN, B, 0, stream>>>(ei, bcur, P);
    k_build<<<NBUCK, B, 0, stream>>>(bcur, P, x, srcidx, offs, endp, dis, xs);

    // fused layer 1 (+ graph bounds), h1 stored as two fp16 half-tables
    k_layer1<<<gN, B, 0, stream>>>(xs, offs, endp, srcidx, dis, bat, W1, b1,
                                   gstart, gend, h1a, h1b);

    // fused layer 2: 2-sub-pass gather (L2-resident tables) -> GEMM+ELU -> pool
    k_layer2<<<N_NODES / L2_NODES, B, 0, stream>>>(
        h1a, h1b, offs, endp, srcidx, dis, bat, W2, b2, sums);

    k_final<<<(N_GRAPHS + 3) / 4, B, 0, stream>>>(sums, gstart, gend, W3, b3, out);
}

// Round 15
// 106.126 us; speedup vs baseline: 1.0962x; 1.0962x over previous
//
#include <hip/hip_runtime.h>
#include <hip/hip_fp16.h>
#include <math.h>

#define N_NODES 50000
#define N_EDGES 1000000
#define N_HID 64
#define N_GRAPHS 500
#define IN_DIM 4
#define NPAD 50048

#define BK_SHIFT 7
#define BK_NODES 128                      // nodes per bucket
#define NBUCK 391                         // ceil(50000/128)
#define BCAP 3072                         // mean 2560 + 10 sigma
#define EPT 16                            // edges per thread in k_bin
#define EPW (EPT * 256)                   // 4096 edges per WG
#define NWG_BIN ((N_EDGES + EPW - 1) / EPW)

// ---------- init: bcur, gstart/gend, pooled sums ----------
__global__ void k_init(int* bcur, int* gstart, int* gend, float* sums) {
    int i = blockIdx.x * blockDim.x + threadIdx.x;
    if (i < 512) { bcur[i] = 0; gstart[i] = 0; gend[i] = 0; }
    if (i < N_GRAPHS * N_HID) sums[i] = 0.f;
}

// ---------- pass A: bin packed (src<<7|dstlocal) by dst bucket ----------
// single-histogram: pass-1 atomic return value IS the local offset.
__global__ void k_bin(const int* __restrict__ ei, int* bcur, int* __restrict__ P) {
    __shared__ int hist[NBUCK];
    __shared__ int base[NBUCK];
    int t = threadIdx.x;
    int wg0 = blockIdx.x * EPW;
    for (int b = t; b < NBUCK; b += 256) hist[b] = 0;
    __syncthreads();

    const int4* s4 = (const int4*)ei;
    const int4* d4 = (const int4*)(ei + N_EDGES);
    int rs[EPT], rd[EPT], rl[EPT];
#pragma unroll
    for (int i = 0; i < 4; ++i) {
        int e = wg0 + (i * 256 + t) * 4;
        if (e < N_EDGES) {
            int4 vs = s4[e >> 2];
            int4 vd = d4[e >> 2];
            rs[i * 4 + 0] = vs.x; rd[i * 4 + 0] = vd.x;
            rs[i * 4 + 1] = vs.y; rd[i * 4 + 1] = vd.y;
            rs[i * 4 + 2] = vs.z; rd[i * 4 + 2] = vd.z;
            rs[i * 4 + 3] = vs.w; rd[i * 4 + 3] = vd.w;
            rl[i * 4 + 0] = atomicAdd(&hist[vd.x >> BK_SHIFT], 1);
            rl[i * 4 + 1] = atomicAdd(&hist[vd.y >> BK_SHIFT], 1);
            rl[i * 4 + 2] = atomicAdd(&hist[vd.z >> BK_SHIFT], 1);
            rl[i * 4 + 3] = atomicAdd(&hist[vd.w >> BK_SHIFT], 1);
        } else {
            rd[i * 4 + 0] = rd[i * 4 + 1] = rd[i * 4 + 2] = rd[i * 4 + 3] = -1;
        }
    }
    __syncthreads();
    for (int b = t; b < NBUCK; b += 256) {
        int h = hist[b];
        base[b] = h ? atomicAdd(&bcur[b], h) : 0;
    }
    __syncthreads();
#pragma unroll
    for (int i = 0; i < EPT; ++i) {
        if (rd[i] >= 0) {
            int bk = rd[i] >> BK_SHIFT;
            int loc = base[bk] + rl[i];
            if (loc > BCAP - 1) loc = BCAP - 1;   // overflow guard (never expected)
            P[(size_t)bk * BCAP + loc] = (rs[i] << BK_SHIFT) | (rd[i] & (BK_NODES - 1));
        }
    }
}

// ---------- pass B: per-bucket counting sort -> CSR rows + dis + xs=x*dis ----------
__global__ void k_build(const int* __restrict__ bcur, const int* __restrict__ P,
                        const float* __restrict__ x,
                        int* __restrict__ srcidx, int* __restrict__ offs,
                        int* __restrict__ endp, float* __restrict__ dis,
                        float* __restrict__ xs) {
    __shared__ int sp[BCAP];
    __shared__ int scnt[BK_NODES];
    __shared__ int sscan[BK_NODES];
    __shared__ int scur[BK_NODES];
    int b = blockIdx.x;
    int t = threadIdx.x;
    int n = bcur[b];
    if (n > BCAP) n = BCAP;
    if (t < BK_NODES) scnt[t] = 0;
    __syncthreads();
    for (int i = t; i < n; i += 256) {
        int v = P[(size_t)b * BCAP + i];
        sp[i] = v;
        atomicAdd(&scnt[v & (BK_NODES - 1)], 1);
    }
    __syncthreads();
    if (t < BK_NODES) sscan[t] = scnt[t];
    __syncthreads();
    for (int d = 1; d < BK_NODES; d <<= 1) {
        int v = 0;
        if (t < BK_NODES && t >= d) v = sscan[t - d];
        __syncthreads();
        if (t < BK_NODES) sscan[t] += v;
        __syncthreads();
    }
    if (t < BK_NODES) {
        int excl = sscan[t] - scnt[t];
        scur[t] = excl;
        int node = b * BK_NODES + t;
        if (node < N_NODES) {
            int o = b * BCAP + excl;
            offs[node] = o;
            endp[node] = o + scnt[t];
            float dd = 1.0f / sqrtf((float)(scnt[t] + 1));
            dis[node] = dd;
            float4 xv = ((const float4*)x)[node];
            xv.x *= dd; xv.y *= dd; xv.z *= dd; xv.w *= dd;
            ((float4*)xs)[node] = xv;
        }
    }
    __syncthreads();
    for (int i = t; i < n; i += 256) {
        int v = sp[i];
        int ln = v & (BK_NODES - 1);
        int pos = b * BCAP + atomicAdd(&scur[ln], 1);
        srcidx[pos] = v >> BK_SHIFT;
    }
}

// ---------- fused layer 1: gbounds + (Ahat*X) + h1s = fp16(ELU(.@W1+b1)*dis) ----------
__global__ void k_layer1(const float* __restrict__ xs, const int* __restrict__ offs,
                         const int* __restrict__ endp, const int* __restrict__ srcidx,
                         const float* __restrict__ dis, const int* __restrict__ batch,
                         const float* __restrict__ W1, const float* __restrict__ b1,
                         int* __restrict__ gstart, int* __restrict__ gend,
                         __half* __restrict__ h1s) {
    __shared__ float4 sagg[256];
    __shared__ float sdis[256];
    __shared__ float sW1[IN_DIM * N_HID];
    __shared__ float sb1[N_HID];
    int t = threadIdx.x;
    int nb = blockIdx.x * 256;
    int i = nb + t;
    sW1[t] = W1[t];                        // 256 = IN_DIM*N_HID
    if (t < N_HID) sb1[t] = b1[t];
    if (i < N_NODES) {
        int g = batch[i];
        if (i == 0 || batch[i - 1] != g) gstart[g] = i;          // no atomics:
        if (i == N_NODES - 1 || batch[i + 1] != g) gend[g] = i + 1;  // batch sorted
        const float4* xs4 = (const float4*)xs;
        float4 a0 = xs4[i];                // self-loop (xs = x*dis)
        float4 a1 = make_float4(0.f, 0.f, 0.f, 0.f);
        float4 a2 = a1, a3 = a1;
        int q = offs[i], e = endp[i];
        for (; q + 4 <= e; q += 4) {       // 4 independent gathers in flight
            int i0 = srcidx[q], i1 = srcidx[q + 1], i2 = srcidx[q + 2], i3 = srcidx[q + 3];
            float4 v0 = xs4[i0], v1 = xs4[i1], v2 = xs4[i2], v3 = xs4[i3];
            a0.x += v0.x; a0.y += v0.y; a0.z += v0.z; a0.w += v0.w;
            a1.x += v1.x; a1.y += v1.y; a1.z += v1.z; a1.w += v1.w;
            a2.x += v2.x; a2.y += v2.y; a2.z += v2.z; a2.w += v2.w;
            a3.x += v3.x; a3.y += v3.y; a3.z += v3.z; a3.w += v3.w;
        }
        for (; q < e; ++q) {
            float4 v = xs4[srcidx[q]];
            a0.x += v.x; a0.y += v.y; a0.z += v.z; a0.w += v.w;
        }
        float dd = dis[i];
        float4 r;
        r.x = (a0.x + a1.x + a2.x + a3.x) * dd;
        r.y = (a0.y + a1.y + a2.y + a3.y) * dd;
        r.z = (a0.z + a1.z + a2.z + a3.z) * dd;
        r.w = (a0.w + a1.w + a2.w + a3.w) * dd;
        sagg[t] = r;
        sdis[t] = dd;
    } else {
        sagg[t] = make_float4(0.f, 0.f, 0.f, 0.f);
        sdis[t] = 0.f;
    }
    __syncthreads();
    int w = t >> 6, j = t & 63;
    float w0 = sW1[0 * N_HID + j], w1 = sW1[1 * N_HID + j];
    float w2 = sW1[2 * N_HID + j], w3 = sW1[3 * N_HID + j];
    float bj = sb1[j];
    for (int n = 0; n < 64; ++n) {
        int local = w * 64 + n;
        int node = nb + local;
        if (node >= N_NODES) break;        // wave-uniform (j not involved)
        float4 a = sagg[local];            // LDS broadcast
        float acc = a.x * w0 + a.y * w1 + a.z * w2 + a.w * w3 + bj;
        acc = acc > 0.f ? acc : expm1f(acc);
        h1s[(size_t)node * N_HID + j] = __float2half_rn(acc * sdis[local]);
    }
}

// ---------- fp16 row-chunk accumulate: raw float4 = 8 halves -> 8 fp32 accs ----------
__device__ inline void acc_half8(float* acc, float4 raw) {
    const __half2* hp = (const __half2*)&raw;
#pragma unroll
    for (int c = 0; c < 4; ++c) {
        float2 f = __half22float2(hp[c]);
        acc[2 * c + 0] += f.x;
        acc[2 * c + 1] += f.y;
    }
}

// ---------- fused layer 2: 4-node pipelined fp16 gather -> GEMM+ELU -> pool ----
// h1s fp16: row = 128 B = exactly 1 cache line per edge (optimal bytes/edge).
// Round-13 was latency-bound at ~2 loads in flight/wave; this version pipelines
// the wave's 4 nodes CONCURRENTLY: each tick issues 8 independent gathers
// (4 nodes x 2) before any accumulation -> ~4x memory-level parallelism.
// NOTE: every __shfl must be executed by ALL 64 lanes (or under wave-UNIFORM
// branches only) — ds_bpermute reads 0 from EXEC-masked source lanes.
// q[nn], nc[nn] are wave-uniform; predicates p0/p1 only guard loads/adds.
#define L2_NODES 16
__global__ void __launch_bounds__(256, 4)
k_layer2(const __half* __restrict__ h1s, const int* __restrict__ offs,
         const int* __restrict__ endp, const int* __restrict__ srcidx,
         const float* __restrict__ dis, const int* __restrict__ batch,
         const float* __restrict__ W2, const float* __restrict__ b2,
         float* __restrict__ sums) {
    __shared__ float sAT[N_HID][L2_NODES + 1];   // [k][n] tmp2, then [feat][n] h2
    __shared__ int sbat[L2_NODES];
    int t = threadIdx.x;  // 256
    int nb = blockIdx.x * L2_NODES;              // 50000/16 = 3125 exact, no tail
    if (t < L2_NODES) sbat[t] = batch[nb + t];

    int wv = t >> 6, lane = t & 63;
    int g = lane >> 3, l = lane & 7;             // 8 groups x 8 lanes
    const float4* hsv = (const float4*)h1s;      // 8 float4 per 128B row
    int nodeA = nb + wv * 4;

    // per-node pipeline state (all wave-uniform except idx)
    int en[4], win[4], q[4], nc[4], idx[4];
    float acc[4][8];
#pragma unroll
    for (int nn = 0; nn < 4; ++nn) {
        int node = nodeA + nn;
        int s = offs[node];
        en[nn] = endp[node];
        win[nn] = s;
        int rem = en[nn] - s;
        nc[nn] = rem > 64 ? 64 : rem;
        q[nn] = 0;
        idx[nn] = (s + lane < en[nn]) ? srcidx[s + lane] : 0;
#pragma unroll
        for (int c = 0; c < 8; ++c) acc[nn][c] = 0.f;
    }
    if (g == 0) {                                // self-loops: 4 loads in flight
#pragma unroll
        for (int nn = 0; nn < 4; ++nn)
            acc_half8(acc[nn], hsv[(size_t)(nodeA + nn) * 8 + l]);
    }

    bool any = (nc[0] > 0) | (nc[1] > 0) | (nc[2] > 0) | (nc[3] > 0);
    while (any) {
        any = false;
        float4 r0[4], r1[4];
        bool p0[4], p1[4], act[4];
        // ---- issue phase: up to 8 independent gathers ----
#pragma unroll
        for (int nn = 0; nn < 4; ++nn) {
            act[nn] = q[nn] < nc[nn];            // wave-uniform
            p0[nn] = p1[nn] = false;
            if (act[nn]) {
                int s0 = __shfl(idx[nn], q[nn] + g);       // q<=48 -> q+8+g<=63
                int s1 = __shfl(idx[nn], q[nn] + 8 + g);
                p0[nn] = q[nn] + g < nc[nn];
                p1[nn] = q[nn] + 8 + g < nc[nn];
                if (p0[nn]) r0[nn] = hsv[(size_t)s0 * 8 + l];
                if (p1[nn]) r1[nn] = hsv[(size_t)s1 * 8 + l];
            }
        }
        // ---- accumulate phase ----
#pragma unroll
        for (int nn = 0; nn < 4; ++nn) {
            if (act[nn]) {
                if (p0[nn]) acc_half8(acc[nn], r0[nn]);
                if (p1[nn]) acc_half8(acc[nn], r1[nn]);
                q[nn] += 16;
                if (q[nn] >= nc[nn] && win[nn] + 64 < en[nn]) {   // refill window
                    win[nn] += 64;
                    int rem = en[nn] - win[nn];
                    nc[nn] = rem > 64 ? 64 : rem;
                    q[nn] = 0;
                    idx[nn] = (win[nn] + lane < en[nn]) ? srcidx[win[nn] + lane] : 0;
                }
                if (q[nn] < nc[nn]) any = true;
            }
        }
    }
    // fold 8 group-partials (xor 8,16,32) — all lanes participate
#pragma unroll
    for (int nn = 0; nn < 4; ++nn) {
#pragma unroll
        for (int c = 0; c < 8; ++c) {
            float v = acc[nn][c];
            v += __shfl_xor(v, 8);
            v += __shfl_xor(v, 16);
            v += __shfl_xor(v, 32);
            acc[nn][c] = v;
        }
    }
    if (g == 0) {
#pragma unroll
        for (int nn = 0; nn < 4; ++nn) {
            float dw = dis[nodeA + nn];
            int local = wv * 4 + nn;
#pragma unroll
            for (int c = 0; c < 8; ++c) sAT[8 * l + c][local] = acc[nn][c] * dw;
        }
    }
    __syncthreads();

    // ---- phase 2: 16x64 GEMM + bias + ELU (thread = 1 node x 4 feats; W2 via L1) ----
    int tj = t & 15, tn = t >> 4;
    const float4* W2v = (const float4*)W2;   // 16 float4 per k-row
    float4 gacc = make_float4(0.f, 0.f, 0.f, 0.f);
#pragma unroll 8
    for (int k = 0; k < N_HID; ++k) {
        float a = sAT[k][tn];                // 16-lane broadcast, conflict-free
        float4 w = W2v[k * 16 + tj];
        gacc.x += a * w.x; gacc.y += a * w.y; gacc.z += a * w.z; gacc.w += a * w.w;
    }
    float4 bb = ((const float4*)b2)[tj];
    __syncthreads();   // everyone done reading sAT before overwrite
    {
        float4 r;
        r.x = gacc.x + bb.x; r.y = gacc.y + bb.y;
        r.z = gacc.z + bb.z; r.w = gacc.w + bb.w;
        r.x = r.x > 0.f ? r.x : expm1f(r.x);
        r.y = r.y > 0.f ? r.y : expm1f(r.y);
        r.z = r.z > 0.f ? r.z : expm1f(r.z);
        r.w = r.w > 0.f ? r.w : expm1f(r.w);
        sAT[4 * tj + 0][tn] = r.x;           // h2 back into sAT as [feat][node]
        sAT[4 * tj + 1][tn] = r.y;
        sAT[4 * tj + 2][tn] = r.z;
        sAT[4 * tj + 3][tn] = r.w;
    }
    __syncthreads();

    // ---- phase 3: per-graph segment pooling (batch sorted; one wave, lane=feat) ----
    if (t < 64) {
        int s = 0;
        while (s < L2_NODES) {
            int gg = sbat[s];
            int e = s + 1;
            while (e < L2_NODES && sbat[e] == gg) ++e;
            float p = 0.f;
            for (int n = s; n < e; ++n) p += sAT[t][n];
            atomicAdd(&sums[gg * N_HID + t], p);
            s = e;
        }
    }
}

// ---------- final: out[g] = dot(sums[g]/cnt, W3) + b3 ; one wave per graph ----------
__global__ void k_final(const float* __restrict__ sums, const int* __restrict__ gstart,
                        const int* __restrict__ gend, const float* __restrict__ W3,
                        const float* __restrict__ b3, float* __restrict__ out) {
    int gid = blockIdx.x * 4 + (threadIdx.x >> 6);
    int j = threadIdx.x & 63;
    if (gid >= N_GRAPHS) return;
    int cnt = gend[gid] - gstart[gid];
    float v = sums[gid * N_HID + j] / (float)(cnt > 0 ? cnt : 1);
    float p = v * W3[j];
#pragma unroll
    for (int off = 32; off; off >>= 1) p += __shfl_down(p, off);
    if (j == 0) out[gid] = p + b3[0];
}

extern "C" void kernel_launch(void* const* d_in, const int* in_sizes, int n_in,
                              void* d_out, int out_size, void* d_ws, size_t ws_size,
                              hipStream_t stream) {
    const float* x   = (const float*)d_in[0];
    const int*   ei  = (const int*)d_in[1];
    const int*   bat = (const int*)d_in[2];
    const float* W1  = (const float*)d_in[3];
    const float* b1  = (const float*)d_in[4];
    const float* W2  = (const float*)d_in[5];
    const float* b2  = (const float*)d_in[6];
    const float* W3  = (const float*)d_in[7];
    const float* b3  = (const float*)d_in[8];
    float* out = (float*)d_out;

    // ---- workspace ----
    char* w = (char*)d_ws;
    int*   bcur   = (int*)w;   w += 512 * 4;
    int*   offs   = (int*)w;   w += NPAD * 4;
    int*   endp   = (int*)w;   w += NPAD * 4;
    float* dis    = (float*)w; w += NPAD * 4;
    int*   gstart = (int*)w;   w += 512 * 4;
    int*   gend   = (int*)w;   w += 512 * 4;
    float* sums   = (float*)w; w += (size_t)N_GRAPHS * N_HID * 4;  // 128 KB
    float* xs     = (float*)w; w += (size_t)NPAD * IN_DIM * 4;     // 800 KB
    int*   srcidx = (int*)w;   w += (size_t)NBUCK * BCAP * 4;      // 4.8 MB
    int*   P      = (int*)w;   w += (size_t)NBUCK * BCAP * 4;      // 4.8 MB
    __half* h1s   = (__half*)w; w += (size_t)N_NODES * N_HID * 2;  // 6.4 MB (fp16)

    const int B = 256;
    const int gN = (N_NODES + B - 1) / B;

    k_init<<<(N_GRAPHS * N_HID + B - 1) / B, B, 0, stream>>>(bcur, gstart, gend, sums);
    k_bin<<<NWG_BIN, B, 0, stream>>>(ei, bcur, P);
    k_build<<<NBUCK, B, 0, stream>>>(bcur, P, x, srcidx, offs, endp, dis, xs);

    // fused layer 1 (+ graph bounds), h1s stored fp16 (128B rows = 1 line/edge)
    k_layer1<<<gN, B, 0, stream>>>(xs, offs, endp, srcidx, dis, bat, W1, b1,
                                   gstart, gend, h1s);

    // fused layer 2: 4-node-pipelined gather -> GEMM+ELU -> pool
    k_layer2<<<N_NODES / L2_NODES, B, 0, stream>>>(
        h1s, offs, endp, srcidx, dis, bat, W2, b2, sums);

    k_final<<<(N_GRAPHS + 3) / 4, B, 0, stream>>>(sums, gstart, gend, W3, b3, out);
}

// Round 16
// 97.006 us; speedup vs baseline: 1.1992x; 1.0940x over previous
//
#include <hip/hip_runtime.h>
#include <hip/hip_fp16.h>
#include <math.h>

#define N_NODES 50000
#define N_EDGES 1000000
#define N_HID 64
#define N_GRAPHS 500
#define IN_DIM 4
#define NPAD 50048

#define BK_SHIFT 7
#define BK_NODES 128                      // nodes per bucket
#define NBUCK 391                         // ceil(50000/128)
#define BCAP 3072                         // mean 2560 + 10 sigma
#define EPT 16                            // edges per thread in k_bin
#define EPW (EPT * 256)                   // 4096 edges per WG
#define NWG_BIN ((N_EDGES + EPW - 1) / EPW)

// ---------- init: bcur, gstart/gend, pooled sums ----------
__global__ void k_init(int* bcur, int* gstart, int* gend, float* sums) {
    int i = blockIdx.x * blockDim.x + threadIdx.x;
    if (i < 512) { bcur[i] = 0; gstart[i] = 0; gend[i] = 0; }
    if (i < N_GRAPHS * N_HID) sums[i] = 0.f;
}

// ---------- pass A: bin packed (src<<7|dstlocal) by dst bucket ----------
// single-histogram: pass-1 atomic return value IS the local offset.
__global__ void k_bin(const int* __restrict__ ei, int* bcur, int* __restrict__ P) {
    __shared__ int hist[NBUCK];
    __shared__ int base[NBUCK];
    int t = threadIdx.x;
    int wg0 = blockIdx.x * EPW;
    for (int b = t; b < NBUCK; b += 256) hist[b] = 0;
    __syncthreads();

    const int4* s4 = (const int4*)ei;
    const int4* d4 = (const int4*)(ei + N_EDGES);
    int rs[EPT], rd[EPT], rl[EPT];
#pragma unroll
    for (int i = 0; i < 4; ++i) {
        int e = wg0 + (i * 256 + t) * 4;
        if (e < N_EDGES) {
            int4 vs = s4[e >> 2];
            int4 vd = d4[e >> 2];
            rs[i * 4 + 0] = vs.x; rd[i * 4 + 0] = vd.x;
            rs[i * 4 + 1] = vs.y; rd[i * 4 + 1] = vd.y;
            rs[i * 4 + 2] = vs.z; rd[i * 4 + 2] = vd.z;
            rs[i * 4 + 3] = vs.w; rd[i * 4 + 3] = vd.w;
            rl[i * 4 + 0] = atomicAdd(&hist[vd.x >> BK_SHIFT], 1);
            rl[i * 4 + 1] = atomicAdd(&hist[vd.y >> BK_SHIFT], 1);
            rl[i * 4 + 2] = atomicAdd(&hist[vd.z >> BK_SHIFT], 1);
            rl[i * 4 + 3] = atomicAdd(&hist[vd.w >> BK_SHIFT], 1);
        } else {
            rd[i * 4 + 0] = rd[i * 4 + 1] = rd[i * 4 + 2] = rd[i * 4 + 3] = -1;
        }
    }
    __syncthreads();
    for (int b = t; b < NBUCK; b += 256) {
        int h = hist[b];
        base[b] = h ? atomicAdd(&bcur[b], h) : 0;
    }
    __syncthreads();
#pragma unroll
    for (int i = 0; i < EPT; ++i) {
        if (rd[i] >= 0) {
            int bk = rd[i] >> BK_SHIFT;
            int loc = base[bk] + rl[i];
            if (loc > BCAP - 1) loc = BCAP - 1;   // overflow guard (never expected)
            P[(size_t)bk * BCAP + loc] = (rs[i] << BK_SHIFT) | (rd[i] & (BK_NODES - 1));
        }
    }
}

// ---------- pass B: per-bucket counting sort -> CSR rows + dis + xs=x*dis ----------
__global__ void k_build(const int* __restrict__ bcur, const int* __restrict__ P,
                        const float* __restrict__ x,
                        int* __restrict__ srcidx, int* __restrict__ offs,
                        int* __restrict__ endp, float* __restrict__ dis,
                        float* __restrict__ xs) {
    __shared__ int sp[BCAP];
    __shared__ int scnt[BK_NODES];
    __shared__ int sscan[BK_NODES];
    __shared__ int scur[BK_NODES];
    int b = blockIdx.x;
    int t = threadIdx.x;
    int n = bcur[b];
    if (n > BCAP) n = BCAP;
    if (t < BK_NODES) scnt[t] = 0;
    __syncthreads();
    for (int i = t; i < n; i += 256) {
        int v = P[(size_t)b * BCAP + i];
        sp[i] = v;
        atomicAdd(&scnt[v & (BK_NODES - 1)], 1);
    }
    __syncthreads();
    if (t < BK_NODES) sscan[t] = scnt[t];
    __syncthreads();
    for (int d = 1; d < BK_NODES; d <<= 1) {
        int v = 0;
        if (t < BK_NODES && t >= d) v = sscan[t - d];
        __syncthreads();
        if (t < BK_NODES) sscan[t] += v;
        __syncthreads();
    }
    if (t < BK_NODES) {
        int excl = sscan[t] - scnt[t];
        scur[t] = excl;
        int node = b * BK_NODES + t;
        if (node < N_NODES) {
            int o = b * BCAP + excl;
            offs[node] = o;
            endp[node] = o + scnt[t];
            float dd = 1.0f / sqrtf((float)(scnt[t] + 1));
            dis[node] = dd;
            float4 xv = ((const float4*)x)[node];
            xv.x *= dd; xv.y *= dd; xv.z *= dd; xv.w *= dd;
            ((float4*)xs)[node] = xv;
        }
    }
    __syncthreads();
    for (int i = t; i < n; i += 256) {
        int v = sp[i];
        int ln = v & (BK_NODES - 1);
        int pos = b * BCAP + atomicAdd(&scur[ln], 1);
        srcidx[pos] = v >> BK_SHIFT;
    }
}

// ---------- fused layer 1: gbounds + (Ahat*X) + h1s = fp16(ELU(.@W1+b1)*dis) ----------
__global__ void k_layer1(const float* __restrict__ xs, const int* __restrict__ offs,
                         const int* __restrict__ endp, const int* __restrict__ srcidx,
                         const float* __restrict__ dis, const int* __restrict__ batch,
                         const float* __restrict__ W1, const float* __restrict__ b1,
                         int* __restrict__ gstart, int* __restrict__ gend,
                         __half* __restrict__ h1s) {
    __shared__ float4 sagg[256];
    __shared__ float sdis[256];
    __shared__ float sW1[IN_DIM * N_HID];
    __shared__ float sb1[N_HID];
    int t = threadIdx.x;
    int nb = blockIdx.x * 256;
    int i = nb + t;
    sW1[t] = W1[t];                        // 256 = IN_DIM*N_HID
    if (t < N_HID) sb1[t] = b1[t];
    if (i < N_NODES) {
        int g = batch[i];
        if (i == 0 || batch[i - 1] != g) gstart[g] = i;          // no atomics:
        if (i == N_NODES - 1 || batch[i + 1] != g) gend[g] = i + 1;  // batch sorted
        const float4* xs4 = (const float4*)xs;
        float4 a0 = xs4[i];                // self-loop (xs = x*dis)
        float4 a1 = make_float4(0.f, 0.f, 0.f, 0.f);
        float4 a2 = a1, a3 = a1;
        int q = offs[i], e = endp[i];
        for (; q + 4 <= e; q += 4) {       // 4 independent gathers in flight
            int i0 = srcidx[q], i1 = srcidx[q + 1], i2 = srcidx[q + 2], i3 = srcidx[q + 3];
            float4 v0 = xs4[i0], v1 = xs4[i1], v2 = xs4[i2], v3 = xs4[i3];
            a0.x += v0.x; a0.y += v0.y; a0.z += v0.z; a0.w += v0.w;
            a1.x += v1.x; a1.y += v1.y; a1.z += v1.z; a1.w += v1.w;
            a2.x += v2.x; a2.y += v2.y; a2.z += v2.z; a2.w += v2.w;
            a3.x += v3.x; a3.y += v3.y; a3.z += v3.z; a3.w += v3.w;
        }
        for (; q < e; ++q) {
            float4 v = xs4[srcidx[q]];
            a0.x += v.x; a0.y += v.y; a0.z += v.z; a0.w += v.w;
        }
        float dd = dis[i];
        float4 r;
        r.x = (a0.x + a1.x + a2.x + a3.x) * dd;
        r.y = (a0.y + a1.y + a2.y + a3.y) * dd;
        r.z = (a0.z + a1.z + a2.z + a3.z) * dd;
        r.w = (a0.w + a1.w + a2.w + a3.w) * dd;
        sagg[t] = r;
        sdis[t] = dd;
    } else {
        sagg[t] = make_float4(0.f, 0.f, 0.f, 0.f);
        sdis[t] = 0.f;
    }
    __syncthreads();
    int w = t >> 6, j = t & 63;
    float w0 = sW1[0 * N_HID + j], w1 = sW1[1 * N_HID + j];
    float w2 = sW1[2 * N_HID + j], w3 = sW1[3 * N_HID + j];
    float bj = sb1[j];
    for (int n = 0; n < 64; ++n) {
        int local = w * 64 + n;
        int node = nb + local;
        if (node >= N_NODES) break;        // wave-uniform (j not involved)
        float4 a = sagg[local];            // LDS broadcast
        float acc = a.x * w0 + a.y * w1 + a.z * w2 + a.w * w3 + bj;
        acc = acc > 0.f ? acc : expm1f(acc);
        h1s[(size_t)node * N_HID + j] = __float2half_rn(acc * sdis[local]);
    }
}

// ---------- fp16 row-chunk accumulate: raw float4 = 8 halves -> 8 fp32 accs ----------
__device__ inline void acc_half8(float* acc, float4 raw) {
    const __half2* hp = (const __half2*)&raw;
#pragma unroll
    for (int c = 0; c < 4; ++c) {
        float2 f = __half22float2(hp[c]);
        acc[2 * c + 0] += f.x;
        acc[2 * c + 1] += f.y;
    }
}

// ---------- standalone agg: one wave per node, fp16 gather, NO barriers ----------
// De-fused from k_layer2: round-8's standalone structure (12.5K blocks, free wave
// scheduling, no straggler coupling) with the fp16 1-line/edge table.
// NOTE: every __shfl must be executed by ALL 64 lanes — ds_bpermute reads 0
// from EXEC-masked source lanes. Only the dependent load/add is predicated.
__global__ void k_agg16(const __half* __restrict__ h1s, const int* __restrict__ offs,
                        const int* __restrict__ endp, const int* __restrict__ srcidx,
                        const float* __restrict__ dis, float* __restrict__ tmp2) {
    int wid = (blockIdx.x * blockDim.x + threadIdx.x) >> 6;
    int lane = threadIdx.x & 63;
    int g = lane >> 3, l = lane & 7;             // 8 groups x 8 lanes
    if (wid >= N_NODES) return;
    const float4* hsv = (const float4*)h1s;      // 8 float4 per 128B row
    float accA[8] = {0.f, 0.f, 0.f, 0.f, 0.f, 0.f, 0.f, 0.f};
    float accB[8] = {0.f, 0.f, 0.f, 0.f, 0.f, 0.f, 0.f, 0.f};
    if (g == 0) acc_half8(accA, hsv[(size_t)wid * 8 + l]);   // self-loop
    int start = offs[wid], end = endp[wid];
    for (int base = start; base < end; base += 64) {
        int nc = end - base; if (nc > 64) nc = 64;
        int myidx = (base + lane < end) ? srcidx[base + lane] : 0;
        int q = 0;
        for (; q + 16 <= nc; q += 16) {          // 2 loads (16 edges) in flight
            int s0 = __shfl(myidx, q + g);
            int s1 = __shfl(myidx, q + 8 + g);
            float4 r0 = hsv[(size_t)s0 * 8 + l];
            float4 r1 = hsv[(size_t)s1 * 8 + l];
            acc_half8(accA, r0);
            acc_half8(accB, r1);
        }
        if (q + 8 <= nc) {                       // full 8-edge step
            int s = __shfl(myidx, q + g);
            acc_half8(accA, hsv[(size_t)s * 8 + l]);
            q += 8;
        }
        {                                        // ragged tail (0-7 edges)
            int s = __shfl(myidx, q + g);        // ALL lanes execute (q+g <= 63)
            if (q + g < nc) acc_half8(accB, hsv[(size_t)s * 8 + l]);
        }
    }
#pragma unroll
    for (int c = 0; c < 8; ++c) accA[c] += accB[c];
#pragma unroll
    for (int c = 0; c < 8; ++c) {                // fold 8 group-partials
        accA[c] += __shfl_xor(accA[c], 8);
        accA[c] += __shfl_xor(accA[c], 16);
        accA[c] += __shfl_xor(accA[c], 32);
    }
    if (g == 0) {                                // lane l holds feats [8l,8l+8)
        float dw = dis[wid];
        float4 v0 = make_float4(accA[0] * dw, accA[1] * dw, accA[2] * dw, accA[3] * dw);
        float4 v1 = make_float4(accA[4] * dw, accA[5] * dw, accA[6] * dw, accA[7] * dw);
        ((float4*)tmp2)[(size_t)wid * 16 + 2 * l] = v0;
        ((float4*)tmp2)[(size_t)wid * 16 + 2 * l + 1] = v1;
    }
}

// ---------- GEMM + ELU + pool: 64 nodes/block, register-tiled, W2 via L1 ----------
#define GP_NODES 64
__global__ void k_gemmpool(const float* __restrict__ tmp2, const int* __restrict__ batch,
                           const float* __restrict__ W2, const float* __restrict__ b2,
                           float* __restrict__ sums) {
    __shared__ float sAT[N_HID][68];       // [k][n] tmp2, then [feat][n] h2
    __shared__ int sbat[GP_NODES];
    int t = threadIdx.x;  // 256
    int nb = blockIdx.x * GP_NODES;
    if (t < GP_NODES) sbat[t] = (nb + t < N_NODES) ? batch[nb + t] : -1;
    {   // stage tmp2 transposed: thread t -> node sn=t>>2, k-range (t&3)*16..+15
        int sn = t >> 2, k0 = (t & 3) * 16;
        int node = nb + sn;
        bool ok = node < N_NODES;
        const float4* a4 = (const float4*)&tmp2[(size_t)(ok ? node : 0) * N_HID];
#pragma unroll
        for (int i = 0; i < 4; ++i) {
            float4 v = ok ? a4[k0 / 4 + i] : make_float4(0.f, 0.f, 0.f, 0.f);
            sAT[k0 + 4 * i + 0][sn] = v.x;
            sAT[k0 + 4 * i + 1][sn] = v.y;
            sAT[k0 + 4 * i + 2][sn] = v.z;
            sAT[k0 + 4 * i + 3][sn] = v.w;
        }
    }
    __syncthreads();
    int tj = t & 15, tn = t >> 4;
    const float4* W2v = (const float4*)W2;   // 16 float4 per k-row (L1-resident)
    float4 acc0 = make_float4(0.f, 0.f, 0.f, 0.f);
    float4 acc1 = acc0, acc2 = acc0, acc3 = acc0;
#pragma unroll 8
    for (int k = 0; k < N_HID; ++k) {
        float4 a = *(const float4*)&sAT[k][4 * tn];
        float4 w = W2v[k * 16 + tj];
        acc0.x += a.x * w.x; acc0.y += a.x * w.y; acc0.z += a.x * w.z; acc0.w += a.x * w.w;
        acc1.x += a.y * w.x; acc1.y += a.y * w.y; acc1.z += a.y * w.z; acc1.w += a.y * w.w;
        acc2.x += a.z * w.x; acc2.y += a.z * w.y; acc2.z += a.z * w.z; acc2.w += a.z * w.w;
        acc3.x += a.w * w.x; acc3.y += a.w * w.y; acc3.z += a.w * w.z; acc3.w += a.w * w.w;
    }
    float4 bb = ((const float4*)b2)[tj];
    __syncthreads();   // everyone done reading sAT before overwrite
    // h2 back into sAT as [feat][node]
#define GP_WB(ACC, I)                                                         \
    {                                                                         \
        float4 r;                                                             \
        r.x = ACC.x + bb.x; r.y = ACC.y + bb.y;                               \
        r.z = ACC.z + bb.z; r.w = ACC.w + bb.w;                               \
        r.x = r.x > 0.f ? r.x : expm1f(r.x);                                  \
        r.y = r.y > 0.f ? r.y : expm1f(r.y);                                  \
        r.z = r.z > 0.f ? r.z : expm1f(r.z);                                  \
        r.w = r.w > 0.f ? r.w : expm1f(r.w);                                  \
        sAT[4 * tj + 0][4 * tn + (I)] = r.x;                                  \
        sAT[4 * tj + 1][4 * tn + (I)] = r.y;                                  \
        sAT[4 * tj + 2][4 * tn + (I)] = r.z;                                  \
        sAT[4 * tj + 3][4 * tn + (I)] = r.w;                                  \
    }
    GP_WB(acc0, 0) GP_WB(acc1, 1) GP_WB(acc2, 2) GP_WB(acc3, 3)
#undef GP_WB
    __syncthreads();
    // per-graph segment pooling (batch sorted; uniform flow; 4 waves)
    int j = t & 63, w = t >> 6;
    int s = 0;
    while (s < GP_NODES) {
        int gg = sbat[s];
        int e = s + 1;
        while (e < GP_NODES && sbat[e] == gg) ++e;
        if (gg >= 0 && s + w < e) {
            float p = 0.f;
            for (int n = s + w; n < e; n += 4) p += sAT[j][n];
            atomicAdd(&sums[gg * N_HID + j], p);
        }
        s = e;
    }
}

// ---------- final: out[g] = dot(sums[g]/cnt, W3) + b3 ; one wave per graph ----------
__global__ void k_final(const float* __restrict__ sums, const int* __restrict__ gstart,
                        const int* __restrict__ gend, const float* __restrict__ W3,
                        const float* __restrict__ b3, float* __restrict__ out) {
    int gid = blockIdx.x * 4 + (threadIdx.x >> 6);
    int j = threadIdx.x & 63;
    if (gid >= N_GRAPHS) return;
    int cnt = gend[gid] - gstart[gid];
    float v = sums[gid * N_HID + j] / (float)(cnt > 0 ? cnt : 1);
    float p = v * W3[j];
#pragma unroll
    for (int off = 32; off; off >>= 1) p += __shfl_down(p, off);
    if (j == 0) out[gid] = p + b3[0];
}

extern "C" void kernel_launch(void* const* d_in, const int* in_sizes, int n_in,
                              void* d_out, int out_size, void* d_ws, size_t ws_size,
                              hipStream_t stream) {
    const float* x   = (const float*)d_in[0];
    const int*   ei  = (const int*)d_in[1];
    const int*   bat = (const int*)d_in[2];
    const float* W1  = (const float*)d_in[3];
    const float* b1  = (const float*)d_in[4];
    const float* W2  = (const float*)d_in[5];
    const float* b2  = (const float*)d_in[6];
    const float* W3  = (const float*)d_in[7];
    const float* b3  = (const float*)d_in[8];
    float* out = (float*)d_out;

    // ---- workspace ----
    char* w = (char*)d_ws;
    int*   bcur   = (int*)w;   w += 512 * 4;
    int*   offs   = (int*)w;   w += NPAD * 4;
    int*   endp   = (int*)w;   w += NPAD * 4;
    float* dis    = (float*)w; w += NPAD * 4;
    int*   gstart = (int*)w;   w += 512 * 4;
    int*   gend   = (int*)w;   w += 512 * 4;
    float* sums   = (float*)w; w += (size_t)N_GRAPHS * N_HID * 4;  // 128 KB
    float* xs     = (float*)w; w += (size_t)NPAD * IN_DIM * 4;     // 800 KB
    int*   srcidx = (int*)w;   w += (size_t)NBUCK * BCAP * 4;      // 4.8 MB
    int*   P      = (int*)w;   w += (size_t)NBUCK * BCAP * 4;      // 4.8 MB
    __half* h1s   = (__half*)w; w += (size_t)N_NODES * N_HID * 2;  // 6.4 MB (fp16)
    float* tmp2   = (float*)w; w += (size_t)N_NODES * N_HID * 4;   // 12.8 MB

    const int B = 256;
    const int gN = (N_NODES + B - 1) / B;
    const int gW = (N_NODES * 64 + B - 1) / B;   // one wave per node

    k_init<<<(N_GRAPHS * N_HID + B - 1) / B, B, 0, stream>>>(bcur, gstart, gend, sums);
    k_bin<<<NWG_BIN, B, 0, stream>>>(ei, bcur, P);
    k_build<<<NBUCK, B, 0, stream>>>(bcur, P, x, srcidx, offs, endp, dis, xs);

    // fused layer 1 (+ graph bounds), h1s stored fp16 (128B rows = 1 line/edge)
    k_layer1<<<gN, B, 0, stream>>>(xs, offs, endp, srcidx, dis, bat, W1, b1,
                                   gstart, gend, h1s);

    // layer 2, de-fused: free-running gather -> GEMM+ELU+pool
    k_agg16<<<gW, B, 0, stream>>>(h1s, offs, endp, srcidx, dis, tmp2);
    k_gemmpool<<<(N_NODES + GP_NODES - 1) / GP_NODES, B, 0, stream>>>(
        tmp2, bat, W2, b2, sums);

    k_final<<<(N_GRAPHS + 3) / 4, B, 0, stream>>>(sums, gstart, gend, W3, b3, out);
}